// Round 10
// baseline (696.168 us; speedup 1.0000x reference)
//
#include <hip/hip_runtime.h>
#include <hip/hip_bf16.h>
#include <math.h>

#define NS 255
#define NB 64
#define NE 200
#define NH 300
#define TS 2048          // shorts per 4KB tile (64 rows x 32 k)
#define NBLK 512

// ws layout (bytes):
//  HbfT  [255][10][TS] bf16 tiled/swizzled  @ 0           (10,444,800)
//  C     [255*64][300] f32                  @ 10,444,800  (19,584,000)
//  AembT [255][7][TS] bf16 tiled/swizzled   @ 30,028,800  ( 7,311,360)
//  BW    [4][5][17][TS] bf16 tiled/swizzled @ 37,340,160  ( 1,392,640)
//  bar   [16] int grid-barrier counters     @ 38,732,800  (        64)

typedef __attribute__((ext_vector_type(8))) short short8;
typedef __attribute__((ext_vector_type(4))) float f32x4;

__device__ __forceinline__ float sigmoidf_(float x) { return 1.0f / (1.0f + __expf(-x)); }
__device__ __forceinline__ unsigned short f2bf(float v) {
    union { __hip_bfloat16 b; unsigned short u; } cv; cv.b = __float2bfloat16(v); return cv.u;
}
__device__ __forceinline__ float bf2f(unsigned short u) {
    union { unsigned short u; __hip_bfloat16 b; } cv; cv.u = u; return __bfloat162float(cv.b);
}
__device__ __forceinline__ int swz(int row, int kk) {
    int g = (kk >> 3) ^ ((row >> 1) & 3);
    return ((row << 2) + g) * 8 + (kk & 7);
}

// grid barrier (R6-proven on plain launch): release-agent fence (writeback
// dirty L2; lines stay resident clean) + relaxed device-scope counter.
// Co-residency: 512 blocks, 12.3KB LDS (13/CU), VGPR<=128 via launch_bounds
// -> 3 blocks/CU capacity = 768 >= 512, so the spin cannot deadlock.
// Readers rely on first-touch-per-XCD or same-XCD producer (see mappings).
__device__ __forceinline__ void gbar(int* c, int tid) {
    __syncthreads();
    if (tid == 0) {
        __builtin_amdgcn_fence(__ATOMIC_RELEASE, "agent");
        __hip_atomic_fetch_add(c, 1, __ATOMIC_RELAXED, __HIP_MEMORY_SCOPE_AGENT);
        while (__hip_atomic_load(c, __ATOMIC_RELAXED, __HIP_MEMORY_SCOPE_AGENT) < NBLK)
            __builtin_amdgcn_s_sleep(2);
    }
    __syncthreads();
}

// half-M chunk loop: A frags 2 (32 rows), B frags 4, 8 MFMA (R8-proven)
template<int NCH>
__device__ __forceinline__ void gemm_h(f32x4 acc[4][2],
    const unsigned short* __restrict__ A, const unsigned short* __restrict__ B,
    int offA, int offB)
{
#pragma unroll
    for (int c = 0; c < NCH; ++c) {
        const unsigned short* At = A + c * TS + offA;
        const unsigned short* Bt = B + c * TS + offB;
        short8 a0 = *(const short8*)(At);
        short8 a1 = *(const short8*)(At + 512);
#pragma unroll
        for (int t = 0; t < 4; ++t) {
            short8 b = *(const short8*)(Bt + t * 512);
            acc[t][0] = __builtin_amdgcn_mfma_f32_16x16x32_bf16(a0, b, acc[t][0], 0, 0, 0);
            acc[t][1] = __builtin_amdgcn_mfma_f32_16x16x32_bf16(a1, b, acc[t][1], 0, 0, 0);
        }
    }
}
// full-M chunk loop: A frags 4, 16 MFMA (R7-proven)
template<int NCH>
__device__ __forceinline__ void gemm_f(f32x4 acc[4][4],
    const unsigned short* __restrict__ A, const unsigned short* __restrict__ B,
    int off)
{
#pragma unroll
    for (int c = 0; c < NCH; ++c) {
        const unsigned short* At = A + c * TS + off;
        const unsigned short* Bt = B + c * TS + off;
        short8 a0 = *(const short8*)(At);
        short8 a1 = *(const short8*)(At + 512);
        short8 a2 = *(const short8*)(At + 1024);
        short8 a3 = *(const short8*)(At + 1536);
#pragma unroll
        for (int t = 0; t < 4; ++t) {
            short8 b = *(const short8*)(Bt + t * 512);
            acc[t][0] = __builtin_amdgcn_mfma_f32_16x16x32_bf16(a0, b, acc[t][0], 0, 0, 0);
            acc[t][1] = __builtin_amdgcn_mfma_f32_16x16x32_bf16(a1, b, acc[t][1], 0, 0, 0);
            acc[t][2] = __builtin_amdgcn_mfma_f32_16x16x32_bf16(a2, b, acc[t][2], 0, 0, 0);
            acc[t][3] = __builtin_amdgcn_mfma_f32_16x16x32_bf16(a3, b, acc[t][3], 0, 0, 0);
        }
    }
}

// internal node task (p, strip s, half): 5 waves = i/o/u/fl/fr (R8-proven)
__device__ __forceinline__ void do_internal(float* smf, int p, int s, int half,
    int tid, const unsigned short* __restrict__ AembT,
    const unsigned short* __restrict__ BW,
    const float* __restrict__ b_iou, const float* __restrict__ b_f,
    unsigned short* __restrict__ HbfT, float* __restrict__ C)
{
    int w = tid >> 6, lane = tid & 63, ln = lane & 15, quad = lane >> 4;
    int l = 2 * p + 1, r = 2 * p + 2;
    int bsel = (w < 4) ? w : 3;
    int g = (quad ^ ((ln >> 1) & 3)) * 8;
    int offA = (half * 32 + ln) * 32 + g;
    int offB = ln * 32 + g;

    const unsigned short* Bsrc = BW + (size_t)(bsel * 5 + s) * 17 * TS;
    const unsigned short* Ae = AembT + (size_t)p * 7 * TS;
    const unsigned short* Hl = HbfT + (size_t)l * 10 * TS;
    const unsigned short* Hr = HbfT + (size_t)r * 10 * TS;

    f32x4 acc[4][2];
#pragma unroll
    for (int t = 0; t < 4; ++t)
#pragma unroll
        for (int q = 0; q < 2; ++q) acc[t][q] = (f32x4){0.f, 0.f, 0.f, 0.f};

    if (w < 3) {
        gemm_h<7>(acc, Ae, Bsrc, offA, offB);
        gemm_h<10>(acc, Hl, Bsrc + 7 * TS, offA, offB);
        gemm_h<10>(acc, Hr, Bsrc + 7 * TS, offA, offB);
    } else {
        gemm_h<7>(acc, Ae, Bsrc, offA, offB);
        gemm_h<10>(acc, (w == 3) ? Hl : Hr, Bsrc + 7 * TS, offA, offB);
    }

    for (int t = 0; t < 4; ++t) {
        __syncthreads();
#pragma unroll
        for (int ms = 0; ms < 2; ++ms)
#pragma unroll
            for (int rr = 0; rr < 4; ++rr)
                smf[w * 544 + (ms * 16 + quad * 4 + rr) * 17 + ln] = acc[t][ms][rr];
        __syncthreads();
        for (int idx = tid; idx < 512; idx += 320) {
            int mm = idx >> 4, n = idx & 15;
            int gm = half * 32 + mm;
            int jj = s * 64 + t * 16 + n;
            bool ok = jj < NH;
            float pi = smf[0 * 544 + mm * 17 + n] + (ok ? b_iou[jj] : 0.f);
            float po = smf[1 * 544 + mm * 17 + n] + (ok ? b_iou[NH + jj] : 0.f);
            float pu = smf[2 * 544 + mm * 17 + n] + (ok ? b_iou[2 * NH + jj] : 0.f);
            float bj = ok ? b_f[jj] : 0.f;
            float fl = sigmoidf_(smf[3 * 544 + mm * 17 + n] + bj);
            float fr = sigmoidf_(smf[4 * 544 + mm * 17 + n] + bj);
            float cl = ok ? C[((size_t)l * NB + gm) * NH + jj] : 0.f;
            float cr = ok ? C[((size_t)r * NB + gm) * NH + jj] : 0.f;
            float cc = sigmoidf_(pi) * tanhf(pu) + fl * cl + fr * cr;
            float hh = sigmoidf_(po) * tanhf(cc);
            if (ok) C[((size_t)p * NB + gm) * NH + jj] = cc;
            HbfT[((size_t)p * 10 + (jj >> 5)) * TS + swz(gm, jj & 31)]
                = ok ? f2bf(hh) : (unsigned short)0;
        }
    }
}

// leaf task (p, strip s): full 64-M, waves 0..2 compute i/o/u (R7-proven)
__device__ __forceinline__ void do_leaf(float* smf, int p, int s,
    int tid, const unsigned short* __restrict__ AembT,
    const unsigned short* __restrict__ BW, const float* __restrict__ b_iou,
    unsigned short* __restrict__ HbfT, float* __restrict__ C)
{
    int w = tid >> 6, lane = tid & 63, ln = lane & 15, quad = lane >> 4;
    int off = ln * 32 + (quad ^ ((ln >> 1) & 3)) * 8;

    f32x4 acc[4][4];
#pragma unroll
    for (int t = 0; t < 4; ++t)
#pragma unroll
        for (int q = 0; q < 4; ++q) acc[t][q] = (f32x4){0.f, 0.f, 0.f, 0.f};

    if (w < 3) {
        const unsigned short* Bsrc = BW + (size_t)(w * 5 + s) * 17 * TS;
        const unsigned short* Ae = AembT + (size_t)p * 7 * TS;
        gemm_f<7>(acc, Ae, Bsrc, off);
    }

    for (int t = 0; t < 4; ++t) {
        __syncthreads();
        if (w < 3)
#pragma unroll
            for (int ms = 0; ms < 4; ++ms)
#pragma unroll
                for (int rr = 0; rr < 4; ++rr)
                    smf[w * 1024 + (ms * 16 + quad * 4 + rr) * 16 + ln] = acc[t][ms][rr];
        __syncthreads();
        for (int idx = tid; idx < 1024; idx += 320) {
            int mm = idx >> 4, n = idx & 15;
            int jj = s * 64 + t * 16 + n;
            bool ok = jj < NH;
            float pi = smf[0 * 1024 + mm * 16 + n] + (ok ? b_iou[jj] : 0.f);
            float po = smf[1 * 1024 + mm * 16 + n] + (ok ? b_iou[NH + jj] : 0.f);
            float pu = smf[2 * 1024 + mm * 16 + n] + (ok ? b_iou[2 * NH + jj] : 0.f);
            float cc = sigmoidf_(pi) * tanhf(pu);
            float hh = sigmoidf_(po) * tanhf(cc);
            if (ok) C[((size_t)p * NB + mm) * NH + jj] = cc;
            HbfT[((size_t)p * 10 + (jj >> 5)) * TS + swz(mm, jj & 31)]
                = ok ? f2bf(hh) : (unsigned short)0;
        }
    }
}

// ---------------- single persistent kernel (PLAIN launch) -------------------
// VGPR capped at 128 by __launch_bounds__(320,4) -> 3 blocks/CU capacity.
__global__ __launch_bounds__(320, 4) void fused_kernel(
    const float* __restrict__ U_iou, const float* __restrict__ U_f,
    const float* __restrict__ W_iou, const float* __restrict__ W_f,
    const float* __restrict__ embed, const int* __restrict__ x,
    const float* __restrict__ b_iou, const float* __restrict__ b_f,
    const float* __restrict__ W_out, const float* __restrict__ b_out,
    unsigned short* __restrict__ BW, unsigned short* __restrict__ AembT,
    unsigned short* __restrict__ HbfT, float* __restrict__ C,
    float* __restrict__ out, int* __restrict__ bar)
{
    __shared__ float smf[3072];   // 12.3 KB: epilogue exchange tiles
    int bid = blockIdx.x;
    int tid = threadIdx.x;

    // ---- phase 0: prep, granule-vectorized (16B short8 stores). 128B lines
    // never span blocks (320 granules = 40 lines per block chunk).
    {
        const int gBW = 4 * 5 * 17 * 256;   // 87040 granules
        const int gAe = NS * 7 * 256;       // 456960
        int total = gBW + gAe;
        int stride = NBLK * 320;
        for (int gi = bid * 320 + tid; gi < total; gi += stride) {
            unsigned short st[8];
            if (gi < gBW) {
                int gg = gi & 255, tile = gi >> 8;
                int row = gg >> 2, pos = gg & 3;
                int kk0 = (pos ^ ((row >> 1) & 3)) << 3;
                int c = tile % 17, t2 = tile / 17;
                int s = t2 % 5, g4 = t2 / 5;
                int j = s * 64 + row;
#pragma unroll
                for (int u = 0; u < 8; ++u) {
                    int kk = kk0 + u; float v = 0.f;
                    if (c < 7) {
                        int k = c * 32 + kk;
                        if (j < NH && k < NE)
                            v = (g4 < 3) ? W_iou[k * 900 + g4 * NH + j] : W_f[k * NH + j];
                    } else {
                        int k = (c - 7) * 32 + kk;
                        if (j < NH && k < NH)
                            v = (g4 < 3) ? U_iou[k * 900 + g4 * NH + j] : U_f[k * NH + j];
                    }
                    st[u] = f2bf(v);
                }
                *(short8*)(BW + (size_t)tile * TS + (row * 4 + pos) * 8) = *(short8*)st;
            } else {
                int gi2 = gi - gBW;
                int gg = gi2 & 255, tile = gi2 >> 8;
                int row = gg >> 2, pos = gg & 3;
                int kk0 = (pos ^ ((row >> 1) & 3)) << 3;
                int c = tile % 7, node = tile / 7;
                int k0 = c * 32 + kk0;
                const float* er = embed + (size_t)x[node * NB + row] * NE;
#pragma unroll
                for (int u = 0; u < 8; ++u)
                    st[u] = (k0 + u < NE) ? f2bf(er[k0 + u]) : (unsigned short)0;
                *(short8*)(AembT + (size_t)tile * TS + (row * 4 + pos) * 8) = *(short8*)st;
            }
        }
    }
    gbar(bar + 0, tid);

    int xcd = bid & 7, slot = bid >> 3;   // slot 0..63 within XCD group

    // ---- leaf d=7: per-xcd 16 nodes x 5 strips = 80 full-M tasks ----
    for (int t = slot; t < 80; t += 64) {
        int o = t % 16, s = t / 16;
        do_leaf(smf, 127 + xcd * 16 + o, s, tid, AembT, BW, b_iou, HbfT, C);
    }
    gbar(bar + 1, tid);

    // ---- levels 6..3: per-xcd m nodes x 5 strips x 2 halves ----
    // subtree mapping: node base+xcd*m+o -> all strips/halves + children on
    // one XCD (C-row 128B lines shared across strips stay single-XCD).
    int bi = 2;
    for (int d = 6; d >= 3; --d) {
        int base = (1 << d) - 1;
        int m = 1 << (d - 3);
        int T = m * 10;
        for (int t = slot; t < T; t += 64) {
            int o = t % m, rest = t / m;
            do_internal(smf, base + xcd * m + o, rest % 5, rest / 5,
                        tid, AembT, BW, b_iou, b_f, HbfT, C);
        }
        gbar(bar + bi++, tid);
    }
    // ---- levels 2..0: node idx on xcd = idx<<(3-d), 10 tasks at bid=xcd+8r
    // (all writers of a node's C/H lines on ONE XCD; child reads cross-XCD
    // are first-touch-after-writeback -> safe)
    for (int d = 2; d >= 0; --d) {
        int n = 1 << d;
        int sh = 3 - d;
        if ((xcd & ((1 << sh) - 1)) == 0 && (xcd >> sh) < n && slot < 10) {
            int idx = xcd >> sh;
            do_internal(smf, n - 1 + idx, slot % 5, slot / 5,
                        tid, AembT, BW, b_iou, b_f, HbfT, C);
        }
        gbar(bar + bi++, tid);
    }

    // ---- out: root -> logits -> log_softmax (root H written on xcd 0;
    // bid 0 is xcd 0 -> same-L2 read) ----
    if (bid == 0 && tid < NB) {
        int b = tid;
        float l0 = 0.f, l1 = 0.f;
#pragma unroll 4
        for (int k = 0; k < NH; ++k) {
            float hk = bf2f(HbfT[(size_t)(k >> 5) * TS + swz(b, k & 31)]);
            l0 += hk * W_out[k * 2];
            l1 += hk * W_out[k * 2 + 1];
        }
        l0 += b_out[0];
        l1 += b_out[1];
        float mx = fmaxf(l0, l1);
        float lse = mx + logf(__expf(l0 - mx) + __expf(l1 - mx));
        out[b * 2 + 0] = l0 - lse;
        out[b * 2 + 1] = l1 - lse;
    }
}

extern "C" void kernel_launch(void* const* d_in, const int* in_sizes, int n_in,
                              void* d_out, int out_size, void* d_ws, size_t ws_size,
                              hipStream_t stream)
{
    const float* U_iou = (const float*)d_in[5];
    const float* U_f   = (const float*)d_in[8];
    const float* W_iou = (const float*)d_in[4];
    const float* W_f   = (const float*)d_in[7];
    const float* embed = (const float*)d_in[3];
    const int*   x     = (const int*)d_in[0];
    const float* b_iou = (const float*)d_in[6];
    const float* b_f   = (const float*)d_in[9];
    const float* W_out = (const float*)d_in[10];
    const float* b_out = (const float*)d_in[11];

    char* ws = (char*)d_ws;
    unsigned short* HbfT  = (unsigned short*)(ws + 0);
    float*          C     = (float*)(ws + 10444800);
    unsigned short* AembT = (unsigned short*)(ws + 30028800);
    unsigned short* BW    = (unsigned short*)(ws + 37340160);
    int*            bar   = (int*)(ws + 38732800);

    hipMemsetAsync(bar, 0, 64, stream);
    fused_kernel<<<NBLK, 320, 0, stream>>>(U_iou, U_f, W_iou, W_f, embed, x,
                                           b_iou, b_f, W_out, b_out,
                                           BW, AembT, HbfT, C,
                                           (float*)d_out, bar);
}

// Round 11
// 593.074 us; speedup vs baseline: 1.1738x; 1.1738x over previous
//
#include <hip/hip_runtime.h>
#include <hip/hip_bf16.h>
#include <math.h>

#define NS 255
#define NB 64
#define NE 200
#define NH 300
#define TS 2048          // shorts per 4KB tile (64 rows x 32 k)
#define NBLK 512

// ws layout (bytes):
//  HbfT  [255][10][TS] bf16 tiled/swizzled  @ 0           (10,444,800)
//  C     [255*64][300] f32                  @ 10,444,800  (19,584,000)
//  AembT [255][7][TS] bf16 tiled/swizzled   @ 30,028,800  ( 7,311,360)
//  BW    [4][5][17][TS] bf16 tiled/swizzled @ 37,340,160  ( 1,392,640)
//  bar   [16] int grid-barrier counters     @ 38,732,800  (        64)

typedef __attribute__((ext_vector_type(8))) short short8;
typedef __attribute__((ext_vector_type(4))) float f32x4;

__device__ __forceinline__ float sigmoidf_(float x) { return 1.0f / (1.0f + __expf(-x)); }
__device__ __forceinline__ unsigned short f2bf(float v) {
    union { __hip_bfloat16 b; unsigned short u; } cv; cv.b = __float2bfloat16(v); return cv.u;
}
__device__ __forceinline__ float bf2f(unsigned short u) {
    union { unsigned short u; __hip_bfloat16 b; } cv; cv.u = u; return __bfloat162float(cv.b);
}
__device__ __forceinline__ int swz(int row, int kk) {
    int g = (kk >> 3) ^ ((row >> 1) & 3);
    return ((row << 2) + g) * 8 + (kk & 7);
}

// device-visible (sc1, write-through-to-L3) stores: no dirty L2 lines ever,
// so grid barriers need NO cache maintenance (the R10 killer: 5120 wbl2s).
__device__ __forceinline__ void st_f32(float* p, float v) {
    __hip_atomic_store(p, v, __ATOMIC_RELAXED, __HIP_MEMORY_SCOPE_AGENT);
}
__device__ __forceinline__ void st_u16(unsigned short* p, unsigned short v) {
    __hip_atomic_store(p, v, __ATOMIC_RELAXED, __HIP_MEMORY_SCOPE_AGENT);
}
__device__ __forceinline__ void st16(void* dst, short8 v) {
    union { short8 v; unsigned long long u[2]; } cv; cv.v = v;
    unsigned long long* p = (unsigned long long*)dst;
    __hip_atomic_store(p,     cv.u[0], __ATOMIC_RELAXED, __HIP_MEMORY_SCOPE_AGENT);
    __hip_atomic_store(p + 1, cv.u[1], __ATOMIC_RELAXED, __HIP_MEMORY_SCOPE_AGENT);
}

// fence-free grid barrier: __syncthreads drains vmcnt (sc1 stores are at the
// coherence point), relaxed device-scope counter, spin, workgroup-acquire
// (compiler barrier only — no buffer_inv, clean L2 lines stay warm).
// Consumers are first-touch per XCD for every cross-barrier line, so no
// acquire-invalidate is needed. Co-residency proven in R10 (occ 29.6%).
__device__ __forceinline__ void gbar(int* c, int tid) {
    __syncthreads();
    if (tid == 0) {
        __hip_atomic_fetch_add(c, 1, __ATOMIC_RELAXED, __HIP_MEMORY_SCOPE_AGENT);
        while (__hip_atomic_load(c, __ATOMIC_RELAXED, __HIP_MEMORY_SCOPE_AGENT) < NBLK)
            __builtin_amdgcn_s_sleep(2);
    }
    __builtin_amdgcn_fence(__ATOMIC_ACQUIRE, "workgroup");
    __syncthreads();
}

// half-M chunk loop: A frags 2 (32 rows), B frags 4, 8 MFMA (R8-proven)
template<int NCH>
__device__ __forceinline__ void gemm_h(f32x4 acc[4][2],
    const unsigned short* __restrict__ A, const unsigned short* __restrict__ B,
    int offA, int offB)
{
#pragma unroll
    for (int c = 0; c < NCH; ++c) {
        const unsigned short* At = A + c * TS + offA;
        const unsigned short* Bt = B + c * TS + offB;
        short8 a0 = *(const short8*)(At);
        short8 a1 = *(const short8*)(At + 512);
#pragma unroll
        for (int t = 0; t < 4; ++t) {
            short8 b = *(const short8*)(Bt + t * 512);
            acc[t][0] = __builtin_amdgcn_mfma_f32_16x16x32_bf16(a0, b, acc[t][0], 0, 0, 0);
            acc[t][1] = __builtin_amdgcn_mfma_f32_16x16x32_bf16(a1, b, acc[t][1], 0, 0, 0);
        }
    }
}
// full-M chunk loop: A frags 4, 16 MFMA (R7-proven)
template<int NCH>
__device__ __forceinline__ void gemm_f(f32x4 acc[4][4],
    const unsigned short* __restrict__ A, const unsigned short* __restrict__ B,
    int off)
{
#pragma unroll
    for (int c = 0; c < NCH; ++c) {
        const unsigned short* At = A + c * TS + off;
        const unsigned short* Bt = B + c * TS + off;
        short8 a0 = *(const short8*)(At);
        short8 a1 = *(const short8*)(At + 512);
        short8 a2 = *(const short8*)(At + 1024);
        short8 a3 = *(const short8*)(At + 1536);
#pragma unroll
        for (int t = 0; t < 4; ++t) {
            short8 b = *(const short8*)(Bt + t * 512);
            acc[t][0] = __builtin_amdgcn_mfma_f32_16x16x32_bf16(a0, b, acc[t][0], 0, 0, 0);
            acc[t][1] = __builtin_amdgcn_mfma_f32_16x16x32_bf16(a1, b, acc[t][1], 0, 0, 0);
            acc[t][2] = __builtin_amdgcn_mfma_f32_16x16x32_bf16(a2, b, acc[t][2], 0, 0, 0);
            acc[t][3] = __builtin_amdgcn_mfma_f32_16x16x32_bf16(a3, b, acc[t][3], 0, 0, 0);
        }
    }
}

// internal node task (p, strip s, half): 5 waves = i/o/u/fl/fr (R8-proven)
__device__ __forceinline__ void do_internal(float* smf, int p, int s, int half,
    int tid, const unsigned short* __restrict__ AembT,
    const unsigned short* __restrict__ BW,
    const float* __restrict__ b_iou, const float* __restrict__ b_f,
    unsigned short* __restrict__ HbfT, float* __restrict__ C)
{
    int w = tid >> 6, lane = tid & 63, ln = lane & 15, quad = lane >> 4;
    int l = 2 * p + 1, r = 2 * p + 2;
    int bsel = (w < 4) ? w : 3;
    int g = (quad ^ ((ln >> 1) & 3)) * 8;
    int offA = (half * 32 + ln) * 32 + g;
    int offB = ln * 32 + g;

    const unsigned short* Bsrc = BW + (size_t)(bsel * 5 + s) * 17 * TS;
    const unsigned short* Ae = AembT + (size_t)p * 7 * TS;
    const unsigned short* Hl = HbfT + (size_t)l * 10 * TS;
    const unsigned short* Hr = HbfT + (size_t)r * 10 * TS;

    f32x4 acc[4][2];
#pragma unroll
    for (int t = 0; t < 4; ++t)
#pragma unroll
        for (int q = 0; q < 2; ++q) acc[t][q] = (f32x4){0.f, 0.f, 0.f, 0.f};

    if (w < 3) {
        gemm_h<7>(acc, Ae, Bsrc, offA, offB);
        gemm_h<10>(acc, Hl, Bsrc + 7 * TS, offA, offB);
        gemm_h<10>(acc, Hr, Bsrc + 7 * TS, offA, offB);
    } else {
        gemm_h<7>(acc, Ae, Bsrc, offA, offB);
        gemm_h<10>(acc, (w == 3) ? Hl : Hr, Bsrc + 7 * TS, offA, offB);
    }

    for (int t = 0; t < 4; ++t) {
        __syncthreads();
#pragma unroll
        for (int ms = 0; ms < 2; ++ms)
#pragma unroll
            for (int rr = 0; rr < 4; ++rr)
                smf[w * 544 + (ms * 16 + quad * 4 + rr) * 17 + ln] = acc[t][ms][rr];
        __syncthreads();
        for (int idx = tid; idx < 512; idx += 320) {
            int mm = idx >> 4, n = idx & 15;
            int gm = half * 32 + mm;
            int jj = s * 64 + t * 16 + n;
            bool ok = jj < NH;
            float pi = smf[0 * 544 + mm * 17 + n] + (ok ? b_iou[jj] : 0.f);
            float po = smf[1 * 544 + mm * 17 + n] + (ok ? b_iou[NH + jj] : 0.f);
            float pu = smf[2 * 544 + mm * 17 + n] + (ok ? b_iou[2 * NH + jj] : 0.f);
            float bj = ok ? b_f[jj] : 0.f;
            float fl = sigmoidf_(smf[3 * 544 + mm * 17 + n] + bj);
            float fr = sigmoidf_(smf[4 * 544 + mm * 17 + n] + bj);
            float cl = ok ? C[((size_t)l * NB + gm) * NH + jj] : 0.f;
            float cr = ok ? C[((size_t)r * NB + gm) * NH + jj] : 0.f;
            float cc = sigmoidf_(pi) * tanhf(pu) + fl * cl + fr * cr;
            float hh = sigmoidf_(po) * tanhf(cc);
            if (ok) st_f32(&C[((size_t)p * NB + gm) * NH + jj], cc);
            st_u16(&HbfT[((size_t)p * 10 + (jj >> 5)) * TS + swz(gm, jj & 31)],
                   ok ? f2bf(hh) : (unsigned short)0);
        }
    }
}

// leaf task (p, strip s): full 64-M, waves 0..2 compute i/o/u (R7-proven)
__device__ __forceinline__ void do_leaf(float* smf, int p, int s,
    int tid, const unsigned short* __restrict__ AembT,
    const unsigned short* __restrict__ BW, const float* __restrict__ b_iou,
    unsigned short* __restrict__ HbfT, float* __restrict__ C)
{
    int w = tid >> 6, lane = tid & 63, ln = lane & 15, quad = lane >> 4;
    int off = ln * 32 + (quad ^ ((ln >> 1) & 3)) * 8;

    f32x4 acc[4][4];
#pragma unroll
    for (int t = 0; t < 4; ++t)
#pragma unroll
        for (int q = 0; q < 4; ++q) acc[t][q] = (f32x4){0.f, 0.f, 0.f, 0.f};

    if (w < 3) {
        const unsigned short* Bsrc = BW + (size_t)(w * 5 + s) * 17 * TS;
        const unsigned short* Ae = AembT + (size_t)p * 7 * TS;
        gemm_f<7>(acc, Ae, Bsrc, off);
    }

    for (int t = 0; t < 4; ++t) {
        __syncthreads();
        if (w < 3)
#pragma unroll
            for (int ms = 0; ms < 4; ++ms)
#pragma unroll
                for (int rr = 0; rr < 4; ++rr)
                    smf[w * 1024 + (ms * 16 + quad * 4 + rr) * 16 + ln] = acc[t][ms][rr];
        __syncthreads();
        for (int idx = tid; idx < 1024; idx += 320) {
            int mm = idx >> 4, n = idx & 15;
            int jj = s * 64 + t * 16 + n;
            bool ok = jj < NH;
            float pi = smf[0 * 1024 + mm * 16 + n] + (ok ? b_iou[jj] : 0.f);
            float po = smf[1 * 1024 + mm * 16 + n] + (ok ? b_iou[NH + jj] : 0.f);
            float pu = smf[2 * 1024 + mm * 16 + n] + (ok ? b_iou[2 * NH + jj] : 0.f);
            float cc = sigmoidf_(pi) * tanhf(pu);
            float hh = sigmoidf_(po) * tanhf(cc);
            if (ok) st_f32(&C[((size_t)p * NB + mm) * NH + jj], cc);
            st_u16(&HbfT[((size_t)p * 10 + (jj >> 5)) * TS + swz(mm, jj & 31)],
                   ok ? f2bf(hh) : (unsigned short)0);
        }
    }
}

// ---------------- single persistent kernel (PLAIN launch, R10-proven) -------
__global__ __launch_bounds__(320, 4) void fused_kernel(
    const float* __restrict__ U_iou, const float* __restrict__ U_f,
    const float* __restrict__ W_iou, const float* __restrict__ W_f,
    const float* __restrict__ embed, const int* __restrict__ x,
    const float* __restrict__ b_iou, const float* __restrict__ b_f,
    const float* __restrict__ W_out, const float* __restrict__ b_out,
    unsigned short* __restrict__ BW, unsigned short* __restrict__ AembT,
    unsigned short* __restrict__ HbfT, float* __restrict__ C,
    float* __restrict__ out, int* __restrict__ bar)
{
    __shared__ float smf[3072];   // 12.3 KB
    int bid = blockIdx.x;
    int tid = threadIdx.x;

    // ---- phase 0: prep (sc1 16B stores -> L3; no dirty L2 anywhere) ----
    {
        const int gBW = 4 * 5 * 17 * 256;   // 87040 granules
        const int gAe = NS * 7 * 256;       // 456960
        int total = gBW + gAe;
        int stride = NBLK * 320;
        for (int gi = bid * 320 + tid; gi < total; gi += stride) {
            unsigned short st[8];
            if (gi < gBW) {
                int gg = gi & 255, tile = gi >> 8;
                int row = gg >> 2, pos = gg & 3;
                int kk0 = (pos ^ ((row >> 1) & 3)) << 3;
                int c = tile % 17, t2 = tile / 17;
                int s = t2 % 5, g4 = t2 / 5;
                int j = s * 64 + row;
#pragma unroll
                for (int u = 0; u < 8; ++u) {
                    int kk = kk0 + u; float v = 0.f;
                    if (c < 7) {
                        int k = c * 32 + kk;
                        if (j < NH && k < NE)
                            v = (g4 < 3) ? W_iou[k * 900 + g4 * NH + j] : W_f[k * NH + j];
                    } else {
                        int k = (c - 7) * 32 + kk;
                        if (j < NH && k < NH)
                            v = (g4 < 3) ? U_iou[k * 900 + g4 * NH + j] : U_f[k * NH + j];
                    }
                    st[u] = f2bf(v);
                }
                st16(BW + (size_t)tile * TS + (row * 4 + pos) * 8, *(short8*)st);
            } else {
                int gi2 = gi - gBW;
                int gg = gi2 & 255, tile = gi2 >> 8;
                int row = gg >> 2, pos = gg & 3;
                int kk0 = (pos ^ ((row >> 1) & 3)) << 3;
                int c = tile % 7, node = tile / 7;
                int k0 = c * 32 + kk0;
                const float* er = embed + (size_t)x[node * NB + row] * NE;
#pragma unroll
                for (int u = 0; u < 8; ++u)
                    st[u] = (k0 + u < NE) ? f2bf(er[k0 + u]) : (unsigned short)0;
                st16(AembT + (size_t)tile * TS + (row * 4 + pos) * 8, *(short8*)st);
            }
        }
    }
    gbar(bar + 0, tid);

    int xcd = bid & 7, slot = bid >> 3;   // slot 0..63 within XCD group

    // ---- leaf d=7: per-xcd 16 nodes x 5 strips = 80 full-M tasks ----
    for (int t = slot; t < 80; t += 64) {
        int o = t % 16, s = t / 16;
        do_leaf(smf, 127 + xcd * 16 + o, s, tid, AembT, BW, b_iou, HbfT, C);
    }
    gbar(bar + 1, tid);

    // ---- levels 6..3: per-xcd m nodes x 5 strips x 2 halves ----
    int bi = 2;
    for (int d = 6; d >= 3; --d) {
        int base = (1 << d) - 1;
        int m = 1 << (d - 3);
        int T = m * 10;
        for (int t = slot; t < T; t += 64) {
            int o = t % m, rest = t / m;
            do_internal(smf, base + xcd * m + o, rest % 5, rest / 5,
                        tid, AembT, BW, b_iou, b_f, HbfT, C);
        }
        gbar(bar + bi++, tid);
    }
    // ---- levels 2..0: node idx on xcd = idx<<(3-d), 10 tasks at bid=xcd+8r
    for (int d = 2; d >= 0; --d) {
        int n = 1 << d;
        int sh = 3 - d;
        if ((xcd & ((1 << sh) - 1)) == 0 && (xcd >> sh) < n && slot < 10) {
            int idx = xcd >> sh;
            do_internal(smf, n - 1 + idx, slot % 5, slot / 5,
                        tid, AembT, BW, b_iou, b_f, HbfT, C);
        }
        gbar(bar + bi++, tid);
    }

    // ---- out: root -> logits -> log_softmax ----
    if (bid == 0 && tid < NB) {
        int b = tid;
        float l0 = 0.f, l1 = 0.f;
#pragma unroll 4
        for (int k = 0; k < NH; ++k) {
            float hk = bf2f(HbfT[(size_t)(k >> 5) * TS + swz(b, k & 31)]);
            l0 += hk * W_out[k * 2];
            l1 += hk * W_out[k * 2 + 1];
        }
        l0 += b_out[0];
        l1 += b_out[1];
        float mx = fmaxf(l0, l1);
        float lse = mx + logf(__expf(l0 - mx) + __expf(l1 - mx));
        out[b * 2 + 0] = l0 - lse;
        out[b * 2 + 1] = l1 - lse;
    }
}

extern "C" void kernel_launch(void* const* d_in, const int* in_sizes, int n_in,
                              void* d_out, int out_size, void* d_ws, size_t ws_size,
                              hipStream_t stream)
{
    const float* U_iou = (const float*)d_in[5];
    const float* U_f   = (const float*)d_in[8];
    const float* W_iou = (const float*)d_in[4];
    const float* W_f   = (const float*)d_in[7];
    const float* embed = (const float*)d_in[3];
    const int*   x     = (const int*)d_in[0];
    const float* b_iou = (const float*)d_in[6];
    const float* b_f   = (const float*)d_in[9];
    const float* W_out = (const float*)d_in[10];
    const float* b_out = (const float*)d_in[11];

    char* ws = (char*)d_ws;
    unsigned short* HbfT  = (unsigned short*)(ws + 0);
    float*          C     = (float*)(ws + 10444800);
    unsigned short* AembT = (unsigned short*)(ws + 30028800);
    unsigned short* BW    = (unsigned short*)(ws + 37340160);
    int*            bar   = (int*)(ws + 38732800);

    hipMemsetAsync(bar, 0, 64, stream);
    fused_kernel<<<NBLK, 320, 0, stream>>>(U_iou, U_f, W_iou, W_f, embed, x,
                                           b_iou, b_f, W_out, b_out,
                                           BW, AembT, HbfT, C,
                                           (float*)d_out, bar);
}

// Round 12
// 274.875 us; speedup vs baseline: 2.5327x; 2.1576x over previous
//
#include <hip/hip_runtime.h>
#include <hip/hip_bf16.h>
#include <math.h>

#define NS 255
#define NB 64
#define NE 200
#define NH 300
#define TS 2048          // shorts per 4KB tile (64 rows x 32 k)
#define HTS 1024         // shorts per half tile (32 rows)

// ws layout (bytes):
//  HbfT  [255][10][TS] bf16 tiled/swizzled  @ 0           (10,444,800)
//  Cf16  [255][10][TS] fp16 tiled/swizzled  @ 10,444,800  (10,444,800)
//  AembT [255][7][TS] bf16 tiled/swizzled   @ 20,889,600  ( 7,311,360)
//  BW    [4][5][17][TS] bf16 tiled/swizzled @ 28,200,960  ( 1,392,640)
//  end 29,593,600 (< 39,168,064 proven available)

typedef __attribute__((ext_vector_type(8))) short short8;
typedef __attribute__((ext_vector_type(4))) float f32x4;

__device__ __forceinline__ float sigmoidf_(float x) { return 1.0f / (1.0f + __expf(-x)); }
__device__ __forceinline__ unsigned short f2bf(float v) {
    union { __hip_bfloat16 b; unsigned short u; } cv; cv.b = __float2bfloat16(v); return cv.u;
}
__device__ __forceinline__ float bf2f(unsigned short u) {
    union { unsigned short u; __hip_bfloat16 b; } cv; cv.u = u; return __bfloat162float(cv.b);
}
__device__ __forceinline__ unsigned short f2h(float v) {
    union { _Float16 h; unsigned short u; } cv; cv.h = (_Float16)v; return cv.u;
}
__device__ __forceinline__ float h2f(unsigned short u) {
    union { unsigned short u; _Float16 h; } cv; cv.u = u; return (float)cv.h;
}
__device__ __forceinline__ int swz(int row, int kk) {
    int g = (kk >> 3) ^ ((row >> 1) & 3);
    return ((row << 2) + g) * 8 + (kk & 7);
}

// ---------------- prep: pre-tile weights + embeddings (R8-proven) -----------
__global__ __launch_bounds__(256) void prep_kernel(
    const float* __restrict__ U_iou, const float* __restrict__ U_f,
    const float* __restrict__ W_iou, const float* __restrict__ W_f,
    const float* __restrict__ embed, const int* __restrict__ x,
    unsigned short* __restrict__ BW, unsigned short* __restrict__ AembT)
{
    const int gBW = 4 * 5 * 17 * 256;   // 87040 granules of 8 shorts
    const int gAe = NS * 7 * 256;       // 456960
    int total = gBW + gAe;
    int stride = gridDim.x * blockDim.x;
    for (int gi = blockIdx.x * blockDim.x + threadIdx.x; gi < total; gi += stride) {
        unsigned short st[8];
        if (gi < gBW) {
            int gg = gi & 255, tile = gi >> 8;
            int row = gg >> 2, pos = gg & 3;
            int kk0 = (pos ^ ((row >> 1) & 3)) << 3;
            int c = tile % 17, t2 = tile / 17;
            int s = t2 % 5, g4 = t2 / 5;
            int j = s * 64 + row;
#pragma unroll
            for (int u = 0; u < 8; ++u) {
                int kk = kk0 + u; float v = 0.f;
                if (c < 7) {
                    int k = c * 32 + kk;
                    if (j < NH && k < NE)
                        v = (g4 < 3) ? W_iou[k * 900 + g4 * NH + j] : W_f[k * NH + j];
                } else {
                    int k = (c - 7) * 32 + kk;
                    if (j < NH && k < NH)
                        v = (g4 < 3) ? U_iou[k * 900 + g4 * NH + j] : U_f[k * NH + j];
                }
                st[u] = f2bf(v);
            }
            *(short8*)(BW + (size_t)tile * TS + (row * 4 + pos) * 8) = *(short8*)st;
        } else {
            int gi2 = gi - gBW;
            int gg = gi2 & 255, tile = gi2 >> 8;
            int row = gg >> 2, pos = gg & 3;
            int kk0 = (pos ^ ((row >> 1) & 3)) << 3;
            int c = tile % 7, node = tile / 7;
            int k0 = c * 32 + kk0;
            const float* er = embed + (size_t)x[node * NB + row] * NE;
#pragma unroll
            for (int u = 0; u < 8; ++u)
                st[u] = (k0 + u < NE) ? f2bf(er[k0 + u]) : (unsigned short)0;
            *(short8*)(AembT + (size_t)tile * TS + (row * 4 + pos) * 8) = *(short8*)st;
        }
    }
}

// chunk loop, 32-row half: A frags 2, B frags 4, 8 MFMA; A-stride templated
// (TS for global tiles, HTS for LDS half-tiles)
template<int NCH, int SA>
__device__ __forceinline__ void gemm2(f32x4 acc[4][2],
    const unsigned short* __restrict__ A, const unsigned short* __restrict__ B)
{
#pragma unroll
    for (int c = 0; c < NCH; ++c) {
        const unsigned short* At = A + c * SA;
        const unsigned short* Bt = B + c * TS;
        short8 a0 = *(const short8*)(At);
        short8 a1 = *(const short8*)(At + 512);
#pragma unroll
        for (int t = 0; t < 4; ++t) {
            short8 b = *(const short8*)(Bt + t * 512);
            acc[t][0] = __builtin_amdgcn_mfma_f32_16x16x32_bf16(a0, b, acc[t][0], 0, 0, 0);
            acc[t][1] = __builtin_amdgcn_mfma_f32_16x16x32_bf16(a1, b, acc[t][1], 0, 0, 0);
        }
    }
}
// full-M chunk loop (leaf): A frags 4, 16 MFMA (R7/R8-proven)
template<int NCH>
__device__ __forceinline__ void gemm_f(f32x4 acc[4][4],
    const unsigned short* __restrict__ A, const unsigned short* __restrict__ B)
{
#pragma unroll
    for (int c = 0; c < NCH; ++c) {
        const unsigned short* At = A + c * TS;
        const unsigned short* Bt = B + c * TS;
        short8 a0 = *(const short8*)(At);
        short8 a1 = *(const short8*)(At + 512);
        short8 a2 = *(const short8*)(At + 1024);
        short8 a3 = *(const short8*)(At + 1536);
#pragma unroll
        for (int t = 0; t < 4; ++t) {
            short8 b = *(const short8*)(Bt + t * 512);
            acc[t][0] = __builtin_amdgcn_mfma_f32_16x16x32_bf16(a0, b, acc[t][0], 0, 0, 0);
            acc[t][1] = __builtin_amdgcn_mfma_f32_16x16x32_bf16(a1, b, acc[t][1], 0, 0, 0);
            acc[t][2] = __builtin_amdgcn_mfma_f32_16x16x32_bf16(a2, b, acc[t][2], 0, 0, 0);
            acc[t][3] = __builtin_amdgcn_mfma_f32_16x16x32_bf16(a3, b, acc[t][3], 0, 0, 0);
        }
    }
}

// ---------------- internal levels: burst-staged children, 5 waves -----------
// task = (node p, strip s, half). Children H (20 half-tiles) + C (4) staged
// into LDS via global_load_lds burst -> ~48KB in flight per block.
__global__ __launch_bounds__(320) void level_kernel(
    const unsigned short* __restrict__ AembT, const unsigned short* __restrict__ BW,
    const float* __restrict__ b_iou, const float* __restrict__ b_f,
    unsigned short* __restrict__ HbfT, unsigned short* __restrict__ Cg,
    int base, int m, int sh)
{
    __shared__ unsigned short sm[24 * HTS];   // 48 KB
    int bid = blockIdx.x;
    int p, s, half;
    if (m > 0) {
        int xcd = bid & 7, idx = bid >> 3;
        int o = idx % m, rest = idx / m;
        p = base + xcd * m + o;
        s = rest % 5; half = rest / 5;
    } else {
        int xcd = bid & 7;
        if (xcd & ((1 << sh) - 1)) return;
        p = base + (xcd >> sh);
        int idx = bid >> 3;
        s = idx % 5; half = idx / 5;
    }
    int tid = threadIdx.x;
    int w = tid >> 6, lane = tid & 63, ln = lane & 15, quad = lane >> 4;
    int l = 2 * p + 1, r = 2 * p + 2;
    int bsel = (w < 4) ? w : 3;
    int gq = (quad ^ ((ln >> 1) & 3)) * 8;
    int offA = (half * 32 + ln) * 32 + gq;   // global A (emb tiles)
    int offL = ln * 32 + gq;                 // LDS A within half-tile
    int offB = ln * 32 + gq;

    // burst-stage: slots 0..9 Hl, 10..19 Hr, 20..21 Cl(2s,2s+1), 22..23 Cr
    for (int idx = w; idx < 24; idx += 5) {
        const unsigned short* gsrc;
        if (idx < 20) {
            int node = (idx < 10) ? l : r;
            int tt = (idx < 10) ? idx : idx - 10;
            gsrc = HbfT + ((size_t)node * 10 + tt) * TS + half * HTS;
        } else {
            int ii = idx - 20;
            int node = (ii < 2) ? l : r;
            gsrc = Cg + ((size_t)node * 10 + 2 * s + (ii & 1)) * TS + half * HTS;
        }
        unsigned short* ldst = sm + idx * HTS;
#pragma unroll
        for (int u = 0; u < 2; ++u)
            __builtin_amdgcn_global_load_lds(
                (const __attribute__((address_space(1))) unsigned short*)(gsrc + u * 512 + lane * 8),
                (__attribute__((address_space(3))) unsigned short*)(ldst + u * 512 + lane * 8),
                16, 0, 0);
    }

    f32x4 acc[4][2];
#pragma unroll
    for (int t = 0; t < 4; ++t)
#pragma unroll
        for (int q = 0; q < 2; ++q) acc[t][q] = (f32x4){0.f, 0.f, 0.f, 0.f};

    // emb contribution while the LDS DMA is in flight (A and B L2/L3-warm)
    const unsigned short* Bsrc = BW + (size_t)(bsel * 5 + s) * 17 * TS;
    const unsigned short* Ae = AembT + (size_t)p * 7 * TS;
    gemm2<7, TS>(acc, Ae + offA, Bsrc + offB);

    __syncthreads();   // compiler emits vmcnt(0): staging complete

    const unsigned short* BH = Bsrc + 7 * TS + offB;
    if (w < 3) {
        gemm2<10, HTS>(acc, sm + offL, BH);             // Hl
        gemm2<10, HTS>(acc, sm + 10 * HTS + offL, BH);  // Hr
    } else if (w == 3) {
        gemm2<10, HTS>(acc, sm + offL, BH);
    } else {
        gemm2<10, HTS>(acc, sm + 10 * HTS + offL, BH);
    }

    // epilogue: smf aliases slots 0..5 (A consumed); C stays in slots 20..23
    float* smf = (float*)sm;
    for (int t = 0; t < 4; ++t) {
        __syncthreads();
#pragma unroll
        for (int ms = 0; ms < 2; ++ms)
#pragma unroll
            for (int rr = 0; rr < 4; ++rr)
                smf[w * 544 + (ms * 16 + quad * 4 + rr) * 17 + ln] = acc[t][ms][rr];
        __syncthreads();
        for (int idx2 = tid; idx2 < 512; idx2 += 320) {
            int mm = idx2 >> 4, n = idx2 & 15;
            int gm = half * 32 + mm;
            int jj = s * 64 + t * 16 + n;
            bool ok = jj < NH;
            float pi = smf[0 * 544 + mm * 17 + n] + (ok ? b_iou[jj] : 0.f);
            float po = smf[1 * 544 + mm * 17 + n] + (ok ? b_iou[NH + jj] : 0.f);
            float pu = smf[2 * 544 + mm * 17 + n] + (ok ? b_iou[2 * NH + jj] : 0.f);
            float bj = ok ? b_f[jj] : 0.f;
            float fl = sigmoidf_(smf[3 * 544 + mm * 17 + n] + bj);
            float fr = sigmoidf_(smf[4 * 544 + mm * 17 + n] + bj);
            int xr = (mm >> 1) & 3;
            int cel = (mm * 4 + ((((t & 1) * 2) + (n >> 3)) ^ xr)) * 8 + (n & 7);
            int ts2 = t >> 1;
            float cl = h2f(sm[(20 + ts2) * HTS + cel]);
            float cr = h2f(sm[(22 + ts2) * HTS + cel]);
            float cc = sigmoidf_(pi) * tanhf(pu) + fl * cl + fr * cr;
            float hh = sigmoidf_(po) * tanhf(cc);
            size_t tbase = ((size_t)p * 10 + (jj >> 5)) * TS + swz(gm, jj & 31);
            if (ok) Cg[tbase] = f2h(cc);
            HbfT[tbase] = ok ? f2bf(hh) : (unsigned short)0;
        }
    }
}

// ---------------- leaf level: 3 waves (i,o,u only), 32-row half (R8) --------
__global__ __launch_bounds__(192) void leaf_kernel(
    const unsigned short* __restrict__ AembT, const unsigned short* __restrict__ BW,
    const float* __restrict__ b_iou,
    unsigned short* __restrict__ HbfT, unsigned short* __restrict__ Cg, int m)
{
    int bid = blockIdx.x;
    int xcd = bid & 7, idx = bid >> 3;
    int o = idx % m, rest = idx / m;
    int p = 127 + xcd * m + o;
    int s = rest % 5;
    int tid = threadIdx.x;
    int w = tid >> 6, lane = tid & 63, ln = lane & 15, quad = lane >> 4;
    int off = ln * 32 + (quad ^ ((ln >> 1) & 3)) * 8;

    const unsigned short* Bsrc = BW + (size_t)(w * 5 + s) * 17 * TS;
    const unsigned short* Ae = AembT + (size_t)p * 7 * TS;

    f32x4 acc[4][4];
#pragma unroll
    for (int t = 0; t < 4; ++t)
#pragma unroll
        for (int q = 0; q < 4; ++q) acc[t][q] = (f32x4){0.f, 0.f, 0.f, 0.f};

    gemm_f<7>(acc, Ae + off, Bsrc + off);

    __shared__ float tile[3][64][16];   // 12 KB
    for (int t = 0; t < 4; ++t) {
        __syncthreads();
#pragma unroll
        for (int ms = 0; ms < 4; ++ms)
#pragma unroll
            for (int rr = 0; rr < 4; ++rr)
                tile[w][ms * 16 + quad * 4 + rr][ln] = acc[t][ms][rr];
        __syncthreads();
        for (int idx2 = tid; idx2 < 1024; idx2 += 192) {
            int mm = idx2 >> 4, n = idx2 & 15;
            int jj = s * 64 + t * 16 + n;
            bool ok = jj < NH;
            float pi = tile[0][mm][n] + (ok ? b_iou[jj] : 0.f);
            float po = tile[1][mm][n] + (ok ? b_iou[NH + jj] : 0.f);
            float pu = tile[2][mm][n] + (ok ? b_iou[2 * NH + jj] : 0.f);
            float cc = sigmoidf_(pi) * tanhf(pu);
            float hh = sigmoidf_(po) * tanhf(cc);
            size_t tbase = ((size_t)p * 10 + (jj >> 5)) * TS + swz(mm, jj & 31);
            if (ok) Cg[tbase] = f2h(cc);
            HbfT[tbase] = ok ? f2bf(hh) : (unsigned short)0;
        }
    }
}

// ---------------- root -> logits -> log_softmax -----------------------------
__global__ __launch_bounds__(64) void out_kernel(
    const unsigned short* __restrict__ HbfT,
    const float* __restrict__ W_out, const float* __restrict__ b_out,
    float* __restrict__ out)
{
    int b = threadIdx.x;
    float l0 = 0.f, l1 = 0.f;
#pragma unroll 4
    for (int k = 0; k < NH; ++k) {
        float hk = bf2f(HbfT[(size_t)(k >> 5) * TS + swz(b, k & 31)]);
        l0 += hk * W_out[k * 2];
        l1 += hk * W_out[k * 2 + 1];
    }
    l0 += b_out[0];
    l1 += b_out[1];
    float m = fmaxf(l0, l1);
    float lse = m + logf(__expf(l0 - m) + __expf(l1 - m));
    out[b * 2 + 0] = l0 - lse;
    out[b * 2 + 1] = l1 - lse;
}

extern "C" void kernel_launch(void* const* d_in, const int* in_sizes, int n_in,
                              void* d_out, int out_size, void* d_ws, size_t ws_size,
                              hipStream_t stream)
{
    const int*   x     = (const int*)d_in[0];
    const float* embed = (const float*)d_in[3];
    const float* W_iou = (const float*)d_in[4];
    const float* U_iou = (const float*)d_in[5];
    const float* b_iou = (const float*)d_in[6];
    const float* W_f   = (const float*)d_in[7];
    const float* U_f   = (const float*)d_in[8];
    const float* b_f   = (const float*)d_in[9];
    const float* W_out = (const float*)d_in[10];
    const float* b_out = (const float*)d_in[11];

    char* ws = (char*)d_ws;
    unsigned short* HbfT  = (unsigned short*)(ws + 0);
    unsigned short* Cg    = (unsigned short*)(ws + 10444800);
    unsigned short* AembT = (unsigned short*)(ws + 20889600);
    unsigned short* BW    = (unsigned short*)(ws + 28200960);

    prep_kernel<<<4096, 256, 0, stream>>>(U_iou, U_f, W_iou, W_f, embed, x, BW, AembT);

    // leaf: 128 nodes x 5 strips, 3 waves each
    leaf_kernel<<<640, 192, 0, stream>>>(AembT, BW, b_iou, HbfT, Cg, 16);
    // internal levels 6..3: 80*m blocks (m nodes per XCD x 5 strips x 2 halves)
    for (int d = 6; d >= 3; --d) {
        int base = (1 << d) - 1;
        int m = 1 << (d - 3);
        level_kernel<<<80 * m, 320, 0, stream>>>(AembT, BW, b_iou, b_f, HbfT, Cg,
                                                 base, m, 0);
    }
    // levels 2..0: 80 blocks, xcd-gated
    for (int d = 2; d >= 0; --d) {
        level_kernel<<<80, 320, 0, stream>>>(AembT, BW, b_iou, b_f, HbfT, Cg,
                                             (1 << d) - 1, 0, 3 - d);
    }
    out_kernel<<<1, 64, 0, stream>>>(HbfT, W_out, b_out, (float*)d_out);
}